// Round 1
// baseline (286.457 us; speedup 1.0000x reference)
//
#include <hip/hip_runtime.h>
#include <hip/hip_bf16.h>
#include <math.h>

typedef __bf16 bf16_t;
typedef bf16_t bf16x8 __attribute__((ext_vector_type(8)));
typedef float f32x4 __attribute__((ext_vector_type(4)));

#define L_TEXT 2048
#define N_TOKEN 2048
#define C_TEXT 3584
#define C_OUT 384
#define C_HID 768
#define BATCH 8
#define MAXROWS (BATCH * N_TOKEN)

// ---------------------------------------------------------------------------
// fp32 -> bf16 conversion (weights)
__global__ __launch_bounds__(256) void cvt_kernel(const float* __restrict__ in,
                                                  bf16_t* __restrict__ out, int n) {
    int i = (blockIdx.x * 256 + threadIdx.x) * 8;
    if (i >= n) return;
    float4 v0 = *(const float4*)(in + i);
    float4 v1 = *(const float4*)(in + i + 4);
    bf16x8 o;
    o[0] = (bf16_t)v0.x; o[1] = (bf16_t)v0.y; o[2] = (bf16_t)v0.z; o[3] = (bf16_t)v0.w;
    o[4] = (bf16_t)v1.x; o[5] = (bf16_t)v1.y; o[6] = (bf16_t)v1.z; o[7] = (bf16_t)v1.w;
    *(bf16x8*)(out + i) = o;
}

// ---------------------------------------------------------------------------
// mapping: for each (batch, chain, cdr) pair, rank-match text CDR tokens to
// protein CDR tokens; emit compact (src_text_row, dst_protein_token) list.
__global__ void map_kernel(const int* __restrict__ tm, const int* __restrict__ ctid,
                           const int* __restrict__ cdrid, const int* __restrict__ bct,
                           const int* __restrict__ brt,
                           int* __restrict__ rows_src, int* __restrict__ rows_dst,
                           int* __restrict__ count) {
    __shared__ int trow[L_TEXT];      // text index by rank
    const int bp = blockIdx.x;        // b*6 + p
    const int b = bp / 6, p = bp % 6;
    const int ct = (p < 3) ? 1 : 2;
    const int rt = 2 + 2 * (p % 3);
    const int lane = threadIdx.x;     // 64 threads = 1 wave
    const unsigned long long ltm = (1ull << lane) - 1ull;

    int base = 0;
    for (int l0 = 0; l0 < L_TEXT; l0 += 64) {
        int l = l0 + lane;
        bool m = (ctid[b * L_TEXT + l] == ct) && (cdrid[b * L_TEXT + l] == rt) &&
                 (tm[b * L_TEXT + l] != 0);
        unsigned long long bal = __ballot(m);
        if (m) trow[base + __popcll(bal & ltm)] = l;
        base += __popcll(bal);
    }
    const int n_text = base;
    __syncthreads();

    base = 0;
    for (int n0 = 0; n0 < N_TOKEN; n0 += 64) {
        int n = n0 + lane;
        bool pm = (bct[b * N_TOKEN + n] == ct) && (brt[b * N_TOKEN + n] == rt);
        unsigned long long bal = __ballot(pm);
        if (pm) {
            int pr = base + __popcll(bal & ltm);
            if (pr < n_text) {
                int i = atomicAdd(count, 1);
                rows_src[i] = b * L_TEXT + trow[pr];
                rows_dst[i] = b * N_TOKEN + n;
            }
        }
        base += __popcll(bal);
    }
}

// ---------------------------------------------------------------------------
// GEMM1: H[m][n] = silu( sum_k X[rows_src[m]][k] * W1[n][k] + b1[n] ), bf16 out
// 128x128 tile, BK=32, 4 waves (2x2), 4x4 16x16x32 fragments per wave.
__global__ __launch_bounds__(256) void gemm1_kernel(
    const float* __restrict__ X, const bf16_t* __restrict__ W1b,
    const float* __restrict__ b1, const int* __restrict__ rows_src,
    const int* __restrict__ countp, bf16_t* __restrict__ H) {
    const int count = *countp;
    const int m0 = blockIdx.x * 128;
    if (m0 >= count) return;
    const int n0 = blockIdx.y * 128;

    __shared__ __align__(16) bf16_t As[128][40];
    __shared__ __align__(16) bf16_t Bs[128][40];

    const int t = threadIdx.x;
    const int lane = t & 63;
    const int w = t >> 6;
    const int wr = w >> 1, wc = w & 1;
    const int fr = lane & 15;
    const int kq = (lane >> 4) * 8;

    f32x4 acc[4][4];
#pragma unroll
    for (int i = 0; i < 4; i++)
#pragma unroll
        for (int j = 0; j < 4; j++) acc[i][j] = (f32x4){0.f, 0.f, 0.f, 0.f};

    // staging assignments: 512 chunks of 8 elems, 2 per thread
    const float* ap[2];
    const bf16_t* bp[2];
    bool av[2];
    int lofs[2];
#pragma unroll
    for (int j = 0; j < 2; j++) {
        int c = t + 256 * j;
        int row = c >> 2;
        int c8 = (c & 3) * 8;
        int gm = m0 + row;
        av[j] = (gm < count);
        int src = av[j] ? rows_src[gm] : 0;
        ap[j] = X + (size_t)src * C_TEXT + c8;
        bp[j] = W1b + (size_t)(n0 + row) * C_TEXT + c8;
        lofs[j] = row * 40 + c8;
    }
    bf16_t* AsF = &As[0][0];
    bf16_t* BsF = &Bs[0][0];

    for (int k0 = 0; k0 < C_TEXT; k0 += 32) {
#pragma unroll
        for (int j = 0; j < 2; j++) {
            bf16x8 val;
            if (av[j]) {
                float4 v0 = *(const float4*)(ap[j] + k0);
                float4 v1 = *(const float4*)(ap[j] + k0 + 4);
                val[0] = (bf16_t)v0.x; val[1] = (bf16_t)v0.y;
                val[2] = (bf16_t)v0.z; val[3] = (bf16_t)v0.w;
                val[4] = (bf16_t)v1.x; val[5] = (bf16_t)v1.y;
                val[6] = (bf16_t)v1.z; val[7] = (bf16_t)v1.w;
            } else {
#pragma unroll
                for (int e = 0; e < 8; e++) val[e] = (bf16_t)0.0f;
            }
            *(bf16x8*)(AsF + lofs[j]) = val;
            *(bf16x8*)(BsF + lofs[j]) = *(const bf16x8*)(bp[j] + k0);
        }
        __syncthreads();
        bf16x8 af[4], bfr[4];
#pragma unroll
        for (int mi = 0; mi < 4; mi++)
            af[mi] = *(const bf16x8*)&As[wr * 64 + mi * 16 + fr][kq];
#pragma unroll
        for (int ni = 0; ni < 4; ni++)
            bfr[ni] = *(const bf16x8*)&Bs[wc * 64 + ni * 16 + fr][kq];
#pragma unroll
        for (int mi = 0; mi < 4; mi++)
#pragma unroll
            for (int ni = 0; ni < 4; ni++)
                acc[mi][ni] = __builtin_amdgcn_mfma_f32_16x16x32_bf16(
                    af[mi], bfr[ni], acc[mi][ni], 0, 0, 0);
        __syncthreads();
    }

    const int rj = (lane >> 4) * 4;
#pragma unroll
    for (int mi = 0; mi < 4; mi++) {
#pragma unroll
        for (int ni = 0; ni < 4; ni++) {
            int gn = n0 + wc * 64 + ni * 16 + fr;
            float bias = b1[gn];
#pragma unroll
            for (int j = 0; j < 4; j++) {
                int gm = m0 + wr * 64 + mi * 16 + rj + j;
                if (gm < count) {
                    float v = acc[mi][ni][j] + bias;
                    float s = v / (1.0f + __expf(-v));
                    H[(size_t)gm * C_HID + gn] = (bf16_t)s;
                }
            }
        }
    }
}

// ---------------------------------------------------------------------------
// GEMM2: out[rows_dst[m]][n] = scale * ( sum_k H[m][k] * W2[n][k] + b2[n] )
__global__ __launch_bounds__(256) void gemm2_kernel(
    const bf16_t* __restrict__ Hm, const bf16_t* __restrict__ W2b,
    const float* __restrict__ b2, const int* __restrict__ rows_dst,
    const int* __restrict__ countp, const float* __restrict__ scale,
    float* __restrict__ out) {
    const int count = *countp;
    const int m0 = blockIdx.x * 128;
    if (m0 >= count) return;
    const int n0 = blockIdx.y * 128;

    __shared__ __align__(16) bf16_t As[128][40];
    __shared__ __align__(16) bf16_t Bs[128][40];

    const int t = threadIdx.x;
    const int lane = t & 63;
    const int w = t >> 6;
    const int wr = w >> 1, wc = w & 1;
    const int fr = lane & 15;
    const int kq = (lane >> 4) * 8;

    f32x4 acc[4][4];
#pragma unroll
    for (int i = 0; i < 4; i++)
#pragma unroll
        for (int j = 0; j < 4; j++) acc[i][j] = (f32x4){0.f, 0.f, 0.f, 0.f};

    const bf16_t* ap[2];
    const bf16_t* bp[2];
    int lofs[2];
#pragma unroll
    for (int j = 0; j < 2; j++) {
        int c = t + 256 * j;
        int row = c >> 2;
        int c8 = (c & 3) * 8;
        ap[j] = Hm + (size_t)(m0 + row) * C_HID + c8;
        bp[j] = W2b + (size_t)(n0 + row) * C_HID + c8;
        lofs[j] = row * 40 + c8;
    }
    bf16_t* AsF = &As[0][0];
    bf16_t* BsF = &Bs[0][0];

    for (int k0 = 0; k0 < C_HID; k0 += 32) {
#pragma unroll
        for (int j = 0; j < 2; j++) {
            *(bf16x8*)(AsF + lofs[j]) = *(const bf16x8*)(ap[j] + k0);
            *(bf16x8*)(BsF + lofs[j]) = *(const bf16x8*)(bp[j] + k0);
        }
        __syncthreads();
        bf16x8 af[4], bfr[4];
#pragma unroll
        for (int mi = 0; mi < 4; mi++)
            af[mi] = *(const bf16x8*)&As[wr * 64 + mi * 16 + fr][kq];
#pragma unroll
        for (int ni = 0; ni < 4; ni++)
            bfr[ni] = *(const bf16x8*)&Bs[wc * 64 + ni * 16 + fr][kq];
#pragma unroll
        for (int mi = 0; mi < 4; mi++)
#pragma unroll
            for (int ni = 0; ni < 4; ni++)
                acc[mi][ni] = __builtin_amdgcn_mfma_f32_16x16x32_bf16(
                    af[mi], bfr[ni], acc[mi][ni], 0, 0, 0);
        __syncthreads();
    }

    const float sc = scale[0];
    const int rj = (lane >> 4) * 4;
#pragma unroll
    for (int mi = 0; mi < 4; mi++) {
#pragma unroll
        for (int ni = 0; ni < 4; ni++) {
            int gn = n0 + wc * 64 + ni * 16 + fr;
            float bias = b2[gn];
#pragma unroll
            for (int j = 0; j < 4; j++) {
                int gm = m0 + wr * 64 + mi * 16 + rj + j;
                if (gm < count) {
                    int dst = rows_dst[gm];
                    out[(size_t)dst * C_OUT + gn] = sc * (acc[mi][ni][j] + bias);
                }
            }
        }
    }
}

// ---------------------------------------------------------------------------
extern "C" void kernel_launch(void* const* d_in, const int* in_sizes, int n_in,
                              void* d_out, int out_size, void* d_ws, size_t ws_size,
                              hipStream_t stream) {
    const float* X     = (const float*)d_in[0];
    const int*   tm    = (const int*)d_in[1];
    const int*   ctid  = (const int*)d_in[2];
    const int*   cdrid = (const int*)d_in[3];
    const int*   bct   = (const int*)d_in[4];
    const int*   brt   = (const int*)d_in[5];
    const float* W1    = (const float*)d_in[6];
    const float* b1    = (const float*)d_in[7];
    const float* W2    = (const float*)d_in[8];
    const float* b2    = (const float*)d_in[9];
    const float* scale = (const float*)d_in[10];

    char* ws = (char*)d_ws;
    size_t off = 0;
    int* count = (int*)(ws + off);           off += 1024;
    int* rows_src = (int*)(ws + off);        off += (size_t)MAXROWS * 4;
    int* rows_dst = (int*)(ws + off);        off += (size_t)MAXROWS * 4;
    bf16_t* W1b = (bf16_t*)(ws + off);       off += (size_t)C_HID * C_TEXT * 2;
    bf16_t* W2b = (bf16_t*)(ws + off);       off += (size_t)C_OUT * C_HID * 2;
    bf16_t* H = (bf16_t*)(ws + off);         off += (size_t)MAXROWS * C_HID * 2;

    hipMemsetAsync(count, 0, 4, stream);
    hipMemsetAsync(d_out, 0, (size_t)out_size * sizeof(float), stream);

    cvt_kernel<<<(C_HID * C_TEXT) / 2048, 256, 0, stream>>>(W1, W1b, C_HID * C_TEXT);
    cvt_kernel<<<(C_OUT * C_HID) / 2048, 256, 0, stream>>>(W2, W2b, C_OUT * C_HID);

    map_kernel<<<BATCH * 6, 64, 0, stream>>>(tm, ctid, cdrid, bct, brt,
                                             rows_src, rows_dst, count);

    dim3 g1(MAXROWS / 128, C_HID / 128);
    gemm1_kernel<<<g1, 256, 0, stream>>>(X, W1b, b1, rows_src, count, H);

    dim3 g2(MAXROWS / 128, C_OUT / 128);
    gemm2_kernel<<<g2, 256, 0, stream>>>(H, W2b, b2, rows_dst, count, scale,
                                         (float*)d_out);
}

// Round 2
// 140.109 us; speedup vs baseline: 2.0445x; 2.0445x over previous
//
#include <hip/hip_runtime.h>
#include <hip/hip_bf16.h>
#include <math.h>

typedef __bf16 bf16_t;
typedef bf16_t bf16x8 __attribute__((ext_vector_type(8)));
typedef bf16_t bf16x4 __attribute__((ext_vector_type(4)));
typedef float f32x4 __attribute__((ext_vector_type(4)));

#define L_TEXT 2048
#define N_TOKEN 2048
#define C_TEXT 3584
#define C_OUT 384
#define C_HID 768
#define BATCH 8
#define MAXROWS (BATCH * N_TOKEN)
#define PM 3072            // capacity for compacted rows (count ~2400 +/- 50)
#define KSPLIT 4
#define KCHUNK (C_TEXT / KSPLIT)   // 896
#define KSPLIT2 2
#define KCHUNK2 (C_HID / KSPLIT2)  // 384

// ---------------------------------------------------------------------------
__global__ __launch_bounds__(256) void cvt_kernel(const float* __restrict__ in,
                                                  bf16_t* __restrict__ out, int n) {
    int i = (blockIdx.x * 256 + threadIdx.x) * 8;
    if (i >= n) return;
    float4 v0 = *(const float4*)(in + i);
    float4 v1 = *(const float4*)(in + i + 4);
    bf16x8 o;
    o[0] = (bf16_t)v0.x; o[1] = (bf16_t)v0.y; o[2] = (bf16_t)v0.z; o[3] = (bf16_t)v0.w;
    o[4] = (bf16_t)v1.x; o[5] = (bf16_t)v1.y; o[6] = (bf16_t)v1.z; o[7] = (bf16_t)v1.w;
    *(bf16x8*)(out + i) = o;
}

// ---------------------------------------------------------------------------
__global__ void map_kernel(const int* __restrict__ tm, const int* __restrict__ ctid,
                           const int* __restrict__ cdrid, const int* __restrict__ bct,
                           const int* __restrict__ brt,
                           int* __restrict__ rows_src, int* __restrict__ rows_dst,
                           int* __restrict__ count) {
    __shared__ int trow[L_TEXT];
    const int bp = blockIdx.x;
    const int b = bp / 6, p = bp % 6;
    const int ct = (p < 3) ? 1 : 2;
    const int rt = 2 + 2 * (p % 3);
    const int lane = threadIdx.x;
    const unsigned long long ltm = (1ull << lane) - 1ull;

    int base = 0;
    for (int l0 = 0; l0 < L_TEXT; l0 += 64) {
        int l = l0 + lane;
        bool m = (ctid[b * L_TEXT + l] == ct) && (cdrid[b * L_TEXT + l] == rt) &&
                 (tm[b * L_TEXT + l] != 0);
        unsigned long long bal = __ballot(m);
        if (m) trow[base + __popcll(bal & ltm)] = l;
        base += __popcll(bal);
    }
    const int n_text = base;
    __syncthreads();

    base = 0;
    for (int n0 = 0; n0 < N_TOKEN; n0 += 64) {
        int n = n0 + lane;
        bool pm = (bct[b * N_TOKEN + n] == ct) && (brt[b * N_TOKEN + n] == rt);
        unsigned long long bal = __ballot(pm);
        if (pm) {
            int pr = base + __popcll(bal & ltm);
            if (pr < n_text) {
                int i = atomicAdd(count, 1);
                rows_src[i] = b * L_TEXT + trow[pr];
                rows_dst[i] = b * N_TOKEN + n;
            }
        }
        base += __popcll(bal);
    }
}

// ---------------------------------------------------------------------------
// GEMM1 (split-K): P[ks][m][n] = sum_{k in chunk ks} X[rows_src[m]][k]*W1[n][k]
// 64x128 tile, BK=32, 4 waves (2x2), wave tile 32x64 (2x4 frags).
// Double-buffered LDS, one barrier per K-step, reg-staged loads issued early.
__global__ __launch_bounds__(256) void gemm1_kernel(
    const float* __restrict__ X, const bf16_t* __restrict__ W1b,
    const int* __restrict__ rows_src, const int* __restrict__ countp,
    float* __restrict__ P) {
    const int count = *countp;
    const int m0 = blockIdx.x * 64;
    if (m0 >= count) return;
    const int n0 = blockIdx.y * 128;
    const int kbeg = blockIdx.z * KCHUNK;

    __shared__ __align__(16) bf16_t As[2][64][40];
    __shared__ __align__(16) bf16_t Bs[2][128][40];

    const int t = threadIdx.x;
    const int lane = t & 63;
    const int w = t >> 6;
    const int wr = w >> 1, wc = w & 1;
    const int fr = lane & 15;
    const int kq = (lane >> 4) * 8;

    f32x4 acc[2][4];
#pragma unroll
    for (int i = 0; i < 2; i++)
#pragma unroll
        for (int j = 0; j < 4; j++) acc[i][j] = (f32x4){0.f, 0.f, 0.f, 0.f};

    // A: 64 rows x 32 cols fp32 -> 256 chunks of 8; 1 per thread
    const int arow = t >> 2, ac8 = (t & 3) * 8;
    const bool av = (m0 + arow < count);
    const float* ap = X + (size_t)(av ? rows_src[m0 + arow] : 0) * C_TEXT + kbeg + ac8;
    const int aofs = arow * 40 + ac8;
    // B: 128 rows x 32 cols bf16 -> 512 chunks; 2 per thread
    const bf16_t* bp[2];
    int bofs[2];
#pragma unroll
    for (int j = 0; j < 2; j++) {
        int c = t + 256 * j;
        int row = c >> 2, c8 = (c & 3) * 8;
        bp[j] = W1b + (size_t)(n0 + row) * C_TEXT + kbeg + c8;
        bofs[j] = row * 40 + c8;
    }

    bf16_t* AsF = &As[0][0][0];
    bf16_t* BsF = &Bs[0][0][0];
    const int ABUF = 64 * 40, BBUF = 128 * 40;

    // prologue: load k-step 0
    bf16x8 ra, rb0, rb1;
    {
        float4 v0 = *(const float4*)(ap);
        float4 v1 = *(const float4*)(ap + 4);
        ra[0] = (bf16_t)v0.x; ra[1] = (bf16_t)v0.y; ra[2] = (bf16_t)v0.z; ra[3] = (bf16_t)v0.w;
        ra[4] = (bf16_t)v1.x; ra[5] = (bf16_t)v1.y; ra[6] = (bf16_t)v1.z; ra[7] = (bf16_t)v1.w;
        if (!av) { for (int e = 0; e < 8; e++) ra[e] = (bf16_t)0.0f; }
        rb0 = *(const bf16x8*)(bp[0]);
        rb1 = *(const bf16x8*)(bp[1]);
    }

    const int T = KCHUNK / 32;   // 28
    for (int tile = 0; tile < T; ++tile) {
        const int cur = tile & 1;
        // commit current regs to LDS[cur]
        *(bf16x8*)(AsF + cur * ABUF + aofs) = ra;
        *(bf16x8*)(BsF + cur * BBUF + bofs[0]) = rb0;
        *(bf16x8*)(BsF + cur * BBUF + bofs[1]) = rb1;
        // issue next-tile loads (latency hides under barrier + MFMA below)
        if (tile + 1 < T) {
            int k = (tile + 1) * 32;
            float4 v0 = *(const float4*)(ap + k);
            float4 v1 = *(const float4*)(ap + k + 4);
            bf16x8 na;
            na[0] = (bf16_t)v0.x; na[1] = (bf16_t)v0.y; na[2] = (bf16_t)v0.z; na[3] = (bf16_t)v0.w;
            na[4] = (bf16_t)v1.x; na[5] = (bf16_t)v1.y; na[6] = (bf16_t)v1.z; na[7] = (bf16_t)v1.w;
            if (!av) { for (int e = 0; e < 8; e++) na[e] = (bf16_t)0.0f; }
            bf16x8 nb0 = *(const bf16x8*)(bp[0] + k);
            bf16x8 nb1 = *(const bf16x8*)(bp[1] + k);
            __syncthreads();
            bf16x8 af[2], bfr[4];
#pragma unroll
            for (int mi = 0; mi < 2; mi++)
                af[mi] = *(const bf16x8*)(AsF + cur * ABUF + (wr * 32 + mi * 16 + fr) * 40 + kq);
#pragma unroll
            for (int ni = 0; ni < 4; ni++)
                bfr[ni] = *(const bf16x8*)(BsF + cur * BBUF + (wc * 64 + ni * 16 + fr) * 40 + kq);
#pragma unroll
            for (int mi = 0; mi < 2; mi++)
#pragma unroll
                for (int ni = 0; ni < 4; ni++)
                    acc[mi][ni] = __builtin_amdgcn_mfma_f32_16x16x32_bf16(
                        af[mi], bfr[ni], acc[mi][ni], 0, 0, 0);
            ra = na; rb0 = nb0; rb1 = nb1;
        } else {
            __syncthreads();
            bf16x8 af[2], bfr[4];
#pragma unroll
            for (int mi = 0; mi < 2; mi++)
                af[mi] = *(const bf16x8*)(AsF + cur * ABUF + (wr * 32 + mi * 16 + fr) * 40 + kq);
#pragma unroll
            for (int ni = 0; ni < 4; ni++)
                bfr[ni] = *(const bf16x8*)(BsF + cur * BBUF + (wc * 64 + ni * 16 + fr) * 40 + kq);
#pragma unroll
            for (int mi = 0; mi < 2; mi++)
#pragma unroll
                for (int ni = 0; ni < 4; ni++)
                    acc[mi][ni] = __builtin_amdgcn_mfma_f32_16x16x32_bf16(
                        af[mi], bfr[ni], acc[mi][ni], 0, 0, 0);
        }
    }

    // write fp32 partials
    float* Pk = P + (size_t)blockIdx.z * PM * C_HID;
    const int rj = (lane >> 4) * 4;
#pragma unroll
    for (int mi = 0; mi < 2; mi++) {
#pragma unroll
        for (int ni = 0; ni < 4; ni++) {
            int gn = n0 + wc * 64 + ni * 16 + fr;
#pragma unroll
            for (int j = 0; j < 4; j++) {
                int gm = m0 + wr * 32 + mi * 16 + rj + j;
                if (gm < count) Pk[(size_t)gm * C_HID + gn] = acc[mi][ni][j];
            }
        }
    }
}

// ---------------------------------------------------------------------------
// reduce partials + bias + SiLU -> H (bf16)
__global__ __launch_bounds__(256) void reduce1_kernel(
    const float* __restrict__ P, const float* __restrict__ b1,
    const int* __restrict__ countp, bf16_t* __restrict__ H) {
    const int count = *countp;
    int idx = blockIdx.x * 256 + threadIdx.x;     // one float4 chunk each
    int m = idx / (C_HID / 4);
    int c = (idx % (C_HID / 4)) * 4;
    if (m >= count) return;
    f32x4 s = *(const f32x4*)(P + (size_t)m * C_HID + c);
#pragma unroll
    for (int ks = 1; ks < KSPLIT; ks++)
        s += *(const f32x4*)(P + ((size_t)ks * PM + m) * C_HID + c);
    f32x4 bb = *(const f32x4*)(b1 + c);
    bf16x4 o;
#pragma unroll
    for (int j = 0; j < 4; j++) {
        float v = s[j] + bb[j];
        o[j] = (bf16_t)(v / (1.0f + __expf(-v)));
    }
    *(bf16x4*)(H + (size_t)m * C_HID + c) = o;
}

// ---------------------------------------------------------------------------
// GEMM2 (split-K=2): P2[ks][m][n] = sum_k H[m][k]*W2[n][k], same tile structure
__global__ __launch_bounds__(256) void gemm2_kernel(
    const bf16_t* __restrict__ Hm, const bf16_t* __restrict__ W2b,
    const int* __restrict__ countp, float* __restrict__ P2) {
    const int count = *countp;
    const int m0 = blockIdx.x * 64;
    if (m0 >= count) return;
    const int n0 = blockIdx.y * 128;
    const int kbeg = blockIdx.z * KCHUNK2;

    __shared__ __align__(16) bf16_t As[2][64][40];
    __shared__ __align__(16) bf16_t Bs[2][128][40];

    const int t = threadIdx.x;
    const int lane = t & 63;
    const int w = t >> 6;
    const int wr = w >> 1, wc = w & 1;
    const int fr = lane & 15;
    const int kq = (lane >> 4) * 8;

    f32x4 acc[2][4];
#pragma unroll
    for (int i = 0; i < 2; i++)
#pragma unroll
        for (int j = 0; j < 4; j++) acc[i][j] = (f32x4){0.f, 0.f, 0.f, 0.f};

    const int arow = t >> 2, ac8 = (t & 3) * 8;
    const bf16_t* ap = Hm + (size_t)(m0 + arow) * C_HID + kbeg + ac8;
    const int aofs = arow * 40 + ac8;
    const bf16_t* bp[2];
    int bofs[2];
#pragma unroll
    for (int j = 0; j < 2; j++) {
        int c = t + 256 * j;
        int row = c >> 2, c8 = (c & 3) * 8;
        bp[j] = W2b + (size_t)(n0 + row) * C_HID + kbeg + c8;
        bofs[j] = row * 40 + c8;
    }

    bf16_t* AsF = &As[0][0][0];
    bf16_t* BsF = &Bs[0][0][0];
    const int ABUF = 64 * 40, BBUF = 128 * 40;

    bf16x8 ra = *(const bf16x8*)(ap);
    bf16x8 rb0 = *(const bf16x8*)(bp[0]);
    bf16x8 rb1 = *(const bf16x8*)(bp[1]);

    const int T = KCHUNK2 / 32;   // 12
    for (int tile = 0; tile < T; ++tile) {
        const int cur = tile & 1;
        *(bf16x8*)(AsF + cur * ABUF + aofs) = ra;
        *(bf16x8*)(BsF + cur * BBUF + bofs[0]) = rb0;
        *(bf16x8*)(BsF + cur * BBUF + bofs[1]) = rb1;
        bf16x8 na, nb0, nb1;
        bool more = (tile + 1 < T);
        if (more) {
            int k = (tile + 1) * 32;
            na = *(const bf16x8*)(ap + k);
            nb0 = *(const bf16x8*)(bp[0] + k);
            nb1 = *(const bf16x8*)(bp[1] + k);
        }
        __syncthreads();
        bf16x8 af[2], bfr[4];
#pragma unroll
        for (int mi = 0; mi < 2; mi++)
            af[mi] = *(const bf16x8*)(AsF + cur * ABUF + (wr * 32 + mi * 16 + fr) * 40 + kq);
#pragma unroll
        for (int ni = 0; ni < 4; ni++)
            bfr[ni] = *(const bf16x8*)(BsF + cur * BBUF + (wc * 64 + ni * 16 + fr) * 40 + kq);
#pragma unroll
        for (int mi = 0; mi < 2; mi++)
#pragma unroll
            for (int ni = 0; ni < 4; ni++)
                acc[mi][ni] = __builtin_amdgcn_mfma_f32_16x16x32_bf16(
                    af[mi], bfr[ni], acc[mi][ni], 0, 0, 0);
        if (more) { ra = na; rb0 = nb0; rb1 = nb1; }
    }

    float* Pk = P2 + (size_t)blockIdx.z * PM * C_OUT;
    const int rj = (lane >> 4) * 4;
#pragma unroll
    for (int mi = 0; mi < 2; mi++) {
#pragma unroll
        for (int ni = 0; ni < 4; ni++) {
            int gn = n0 + wc * 64 + ni * 16 + fr;
#pragma unroll
            for (int j = 0; j < 4; j++) {
                int gm = m0 + wr * 32 + mi * 16 + rj + j;
                if (gm < count) Pk[(size_t)gm * C_OUT + gn] = acc[mi][ni][j];
            }
        }
    }
}

// ---------------------------------------------------------------------------
// reduce partials + bias, scale, scatter to d_out
__global__ __launch_bounds__(256) void epilogue2_kernel(
    const float* __restrict__ P2, const float* __restrict__ b2,
    const int* __restrict__ rows_dst, const int* __restrict__ countp,
    const float* __restrict__ scale, float* __restrict__ out) {
    const int count = *countp;
    int idx = blockIdx.x * 256 + threadIdx.x;
    int m = idx / (C_OUT / 4);
    int c = (idx % (C_OUT / 4)) * 4;
    if (m >= count) return;
    f32x4 s = *(const f32x4*)(P2 + (size_t)m * C_OUT + c);
#pragma unroll
    for (int ks = 1; ks < KSPLIT2; ks++)
        s += *(const f32x4*)(P2 + ((size_t)ks * PM + m) * C_OUT + c);
    f32x4 bb = *(const f32x4*)(b2 + c);
    const float sc = scale[0];
    int dst = rows_dst[m];
    f32x4 o;
#pragma unroll
    for (int j = 0; j < 4; j++) o[j] = sc * (s[j] + bb[j]);
    *(f32x4*)(out + (size_t)dst * C_OUT + c) = o;
}

// ---------------------------------------------------------------------------
extern "C" void kernel_launch(void* const* d_in, const int* in_sizes, int n_in,
                              void* d_out, int out_size, void* d_ws, size_t ws_size,
                              hipStream_t stream) {
    const float* X     = (const float*)d_in[0];
    const int*   tm    = (const int*)d_in[1];
    const int*   ctid  = (const int*)d_in[2];
    const int*   cdrid = (const int*)d_in[3];
    const int*   bct   = (const int*)d_in[4];
    const int*   brt   = (const int*)d_in[5];
    const float* W1    = (const float*)d_in[6];
    const float* b1    = (const float*)d_in[7];
    const float* W2    = (const float*)d_in[8];
    const float* b2    = (const float*)d_in[9];
    const float* scale = (const float*)d_in[10];

    char* ws = (char*)d_ws;
    size_t off = 0;
    int* count = (int*)(ws + off);        off += 1024;
    int* rows_src = (int*)(ws + off);     off += (size_t)MAXROWS * 4;
    int* rows_dst = (int*)(ws + off);     off += (size_t)MAXROWS * 4;
    bf16_t* W1b = (bf16_t*)(ws + off);    off += (size_t)C_HID * C_TEXT * 2;
    bf16_t* W2b = (bf16_t*)(ws + off);    off += (size_t)C_OUT * C_HID * 2;
    bf16_t* H = (bf16_t*)(ws + off);      off += (size_t)PM * C_HID * 2;
    float* P = (float*)(ws + off);        off += (size_t)KSPLIT * PM * C_HID * 4;
    float* P2 = P;   // safe alias: P fully consumed by reduce1 before gemm2 runs

    hipMemsetAsync(count, 0, 4, stream);
    hipMemsetAsync(d_out, 0, (size_t)out_size * sizeof(float), stream);

    cvt_kernel<<<(C_HID * C_TEXT) / 2048, 256, 0, stream>>>(W1, W1b, C_HID * C_TEXT);
    cvt_kernel<<<(C_OUT * C_HID) / 2048, 256, 0, stream>>>(W2, W2b, C_OUT * C_HID);

    map_kernel<<<BATCH * 6, 64, 0, stream>>>(tm, ctid, cdrid, bct, brt,
                                             rows_src, rows_dst, count);

    dim3 g1(PM / 64, C_HID / 128, KSPLIT);          // 48 x 6 x 4
    gemm1_kernel<<<g1, 256, 0, stream>>>(X, W1b, rows_src, count, P);

    reduce1_kernel<<<(PM * C_HID / 4) / 256, 256, 0, stream>>>(P, b1, count, H);

    dim3 g2(PM / 64, C_OUT / 128, KSPLIT2);         // 48 x 3 x 2
    gemm2_kernel<<<g2, 256, 0, stream>>>(H, W2b, count, P2);

    epilogue2_kernel<<<(PM * C_OUT / 4) / 256, 256, 0, stream>>>(
        P2, b2, rows_dst, count, scale, (float*)d_out);
}